// Round 2
// baseline (347.651 us; speedup 1.0000x reference)
//
#include <hip/hip_runtime.h>

#define NN 50000
#define NE 800000
#define NH 64
#define NG 500
#define NPAD 50176   // 196*256
#define NBKT 782     // ceil(NN/64) 64-node buckets
#define CAP 1536     // padded bucket capacity (max bucket deg ~1130; 4.5+ sigma margin)
#define ZR NN        // dedicated zero row in hWbf buffers (zeroed once in k_prep)

typedef __attribute__((ext_vector_type(8))) short bf16x8;   // 8 bf16 = 4 VGPR (MFMA A/B frag)
typedef __attribute__((ext_vector_type(4))) float f32x4;    // MFMA C/D frag

// fp32 -> bf16 round-to-nearest-even
__device__ __forceinline__ unsigned short f2bf(float f) {
  unsigned x = __float_as_uint(f);
  unsigned r = ((x >> 16) & 1u) + 0x7fffu;
  return (unsigned short)((x + r) >> 16);
}
__device__ __forceinline__ float bf2f(unsigned short u) {
  return __uint_as_float(((unsigned)u) << 16);
}

// ---------------- prep: W fragments + zero bcur/out/zero-rows (replaces memset + wprep) ----------------
// Fragment convention (16x16x32 bf16): lane = (idx&15) + 16*kb; element e <-> k = s*32 + kb*8 + e.
// fid = mat*16 + part*8 + s*4 + ntile; mat: 0=conv 1=res; part: 0=bf16-hi 1=bf16-lo.

__global__ __launch_bounds__(256) void k_prep(const float* __restrict__ Wc, const float* __restrict__ Wr,
                                              unsigned short* __restrict__ Wf,
                                              int* __restrict__ bcur, float* __restrict__ out,
                                              unsigned short* __restrict__ hWA, unsigned short* __restrict__ hWB) {
  if (blockIdx.x == 8) {
    int tt = threadIdx.x;
    for (int i = tt; i < 1024; i += 256) bcur[i] = 0;
    for (int i = tt; i < NG; i += 256) out[i] = 0.f;
    if (tt < 32) {
      ((unsigned*)(hWA + (size_t)ZR * 64))[tt] = 0u;
      ((unsigned*)(hWB + (size_t)ZR * 64))[tt] = 0u;
    }
    return;
  }
  int t = blockIdx.x * 256 + threadIdx.x;   // 2048 threads = 32 frags * 64 lanes
  int fid = t >> 6;
  int lane = t & 63;
  int ntile = fid & 3, s = (fid >> 2) & 1, part = (fid >> 3) & 1, mat = fid >> 4;
  const float* W = mat ? Wr : Wc;
  int col = ntile * 16 + (lane & 15);
  int k0 = s * 32 + (lane >> 4) * 8;
#pragma unroll
  for (int e = 0; e < 8; e++) {
    float w = W[(k0 + e) * 64 + col];
    unsigned short h = f2bf(w);
    Wf[(size_t)fid * 512 + lane * 8 + e] = part ? f2bf(w - bf2f(h)) : h;
  }
}

// ---------------- binning into padded buckets: colp[b*CAP + r] ----------------

__global__ __launch_bounds__(256) void k_bin(const int* __restrict__ src, const int* __restrict__ dst,
                                             int* __restrict__ bcur, int* __restrict__ colp) {
  __shared__ int hist[NBKT];
  __shared__ int gbase[NBKT];
  int t = threadIdx.x;
  for (int b = t; b < NBKT; b += 256) hist[b] = 0;
  __syncthreads();
  int e0 = blockIdx.x * 8192;
#pragma unroll
  for (int i = 0; i < 32; i++) {
    int e = e0 + i * 256 + t;
    if (e < NE) atomicAdd(&hist[dst[e] >> 6], 1);
  }
  __syncthreads();
  for (int b = t; b < NBKT; b += 256) {
    int c = hist[b];
    gbase[b] = c ? atomicAdd(&bcur[b], c) : 0;
    hist[b] = 0;  // reuse as rank counter
  }
  __syncthreads();
#pragma unroll
  for (int i = 0; i < 32; i++) {
    int e = e0 + i * 256 + t;
    if (e < NE) {
      int s = src[e], d = dst[e];
      int b = d >> 6;
      int r = atomicAdd(&hist[b], 1);
      colp[b * CAP + gbase[b] + r] = (s << 6) | (d & 63);
    }
  }
}

// ---------------- shared gemm tile body (MFMA, LDS-free, split-bf16) ----------------
// NJT = n-tiles per wave (4 => 64 cols, 2 => 32 cols starting at jbase*16).
// MODE 0: X = Xin. MODE 1: X = relu(Xin + dinv[n]*bf2f(gsum[n])).

template <int NJT, int MODE>
__device__ __forceinline__ void gemm_tile(int lane, int n0, int jbase,
                                          const float* __restrict__ Xin,
                                          const unsigned short* __restrict__ gsum,
                                          const unsigned short* __restrict__ Wf,
                                          const float* __restrict__ cb, const float* __restrict__ rb,
                                          const float* __restrict__ dinv,
                                          unsigned short* __restrict__ hWout, float* __restrict__ agg) {
  int col16 = lane & 15;
  int kb = lane >> 4;
  int nr = n0 + col16;
  int nc = nr < NN ? nr : NN - 1;   // clamp loads; garbage rows never stored
  const float* xrow = Xin + (size_t)nc * 64;
  float v0[8], v1[8];
  {
    float4 a = *(const float4*)(xrow + kb * 8);
    float4 b4 = *(const float4*)(xrow + kb * 8 + 4);
    float4 c = *(const float4*)(xrow + 32 + kb * 8);
    float4 d = *(const float4*)(xrow + 32 + kb * 8 + 4);
    v0[0] = a.x; v0[1] = a.y; v0[2] = a.z; v0[3] = a.w;
    v0[4] = b4.x; v0[5] = b4.y; v0[6] = b4.z; v0[7] = b4.w;
    v1[0] = c.x; v1[1] = c.y; v1[2] = c.z; v1[3] = c.w;
    v1[4] = d.x; v1[5] = d.y; v1[6] = d.z; v1[7] = d.w;
  }
  if (MODE) {
    float dvn = dinv[nc];
    const unsigned* grow = (const unsigned*)(gsum + (size_t)nc * 64);
    uint4 g0 = *(const uint4*)(grow + kb * 4);
    uint4 g1 = *(const uint4*)(grow + 16 + kb * 4);
    unsigned ga[4] = {g0.x, g0.y, g0.z, g0.w};
    unsigned gb[4] = {g1.x, g1.y, g1.z, g1.w};
#pragma unroll
    for (int e = 0; e < 4; e++) {
      v0[2 * e]     = fmaxf(v0[2 * e]     + dvn * bf2f((unsigned short)(ga[e] & 0xffff)), 0.f);
      v0[2 * e + 1] = fmaxf(v0[2 * e + 1] + dvn * bf2f((unsigned short)(ga[e] >> 16)), 0.f);
      v1[2 * e]     = fmaxf(v1[2 * e]     + dvn * bf2f((unsigned short)(gb[e] & 0xffff)), 0.f);
      v1[2 * e + 1] = fmaxf(v1[2 * e + 1] + dvn * bf2f((unsigned short)(gb[e] >> 16)), 0.f);
    }
  }
  bf16x8 ah0, al0, ah1, al1;
#pragma unroll
  for (int e = 0; e < 8; e++) {
    unsigned short h0 = f2bf(v0[e]);
    ah0[e] = (short)h0;
    al0[e] = (short)f2bf(v0[e] - bf2f(h0));
    unsigned short h1 = f2bf(v1[e]);
    ah1[e] = (short)h1;
    al1[e] = (short)f2bf(v1[e] - bf2f(h1));
  }

  f32x4 aC[NJT], aR[NJT];
#pragma unroll
  for (int j = 0; j < NJT; j++) {
    aC[j] = (f32x4){0.f, 0.f, 0.f, 0.f};
    aR[j] = (f32x4){0.f, 0.f, 0.f, 0.f};
  }
  const bf16x8* WFv = (const bf16x8*)Wf;
#pragma unroll
  for (int j = 0; j < NJT; j++) {
    int jj = jbase + j;
    bf16x8 wch0 = WFv[(jj)      * 64 + lane];
    bf16x8 wch1 = WFv[(4 + jj)  * 64 + lane];
    bf16x8 wcl0 = WFv[(8 + jj)  * 64 + lane];
    bf16x8 wcl1 = WFv[(12 + jj) * 64 + lane];
    bf16x8 wrh0 = WFv[(16 + jj) * 64 + lane];
    bf16x8 wrh1 = WFv[(20 + jj) * 64 + lane];
    bf16x8 wrl0 = WFv[(24 + jj) * 64 + lane];
    bf16x8 wrl1 = WFv[(28 + jj) * 64 + lane];
    f32x4 c = aC[j];
    c = __builtin_amdgcn_mfma_f32_16x16x32_bf16(ah0, wch0, c, 0, 0, 0);
    c = __builtin_amdgcn_mfma_f32_16x16x32_bf16(ah1, wch1, c, 0, 0, 0);
    c = __builtin_amdgcn_mfma_f32_16x16x32_bf16(al0, wch0, c, 0, 0, 0);
    c = __builtin_amdgcn_mfma_f32_16x16x32_bf16(al1, wch1, c, 0, 0, 0);
    c = __builtin_amdgcn_mfma_f32_16x16x32_bf16(ah0, wcl0, c, 0, 0, 0);
    c = __builtin_amdgcn_mfma_f32_16x16x32_bf16(ah1, wcl1, c, 0, 0, 0);
    aC[j] = c;
    f32x4 r = aR[j];
    r = __builtin_amdgcn_mfma_f32_16x16x32_bf16(ah0, wrh0, r, 0, 0, 0);
    r = __builtin_amdgcn_mfma_f32_16x16x32_bf16(ah1, wrh1, r, 0, 0, 0);
    r = __builtin_amdgcn_mfma_f32_16x16x32_bf16(al0, wrh0, r, 0, 0, 0);
    r = __builtin_amdgcn_mfma_f32_16x16x32_bf16(al1, wrh1, r, 0, 0, 0);
    r = __builtin_amdgcn_mfma_f32_16x16x32_bf16(ah0, wrl0, r, 0, 0, 0);
    r = __builtin_amdgcn_mfma_f32_16x16x32_bf16(ah1, wrl1, r, 0, 0, 0);
    aR[j] = r;
  }

  // epilogue: D layout col=lane&15, row=(lane>>4)*4+reg
  float cbv[NJT], rbv[NJT];
#pragma unroll
  for (int j = 0; j < NJT; j++) {
    cbv[j] = cb[(jbase + j) * 16 + col16];
    rbv[j] = rb[(jbase + j) * 16 + col16];
  }
  int rbase = kb * 4;
#pragma unroll
  for (int r = 0; r < 4; r++) {
    int node = n0 + rbase + r;
    if (node < NN) {
      float dv = dinv[node];
      size_t o = (size_t)node * 64 + col16;
#pragma unroll
      for (int j = 0; j < NJT; j++) {
        int jj = jbase + j;
        float hc = dv * aC[j][r];
        unsigned short hb = f2bf(hc);
        hWout[o + jj * 16] = hb;
        agg[o + jj * 16] = aR[j][r] + rbv[j] + cbv[j] + dv * hc;
      }
    }
  }
}

// ---------------- fused: bucket CSR + encoder + gemm0 (block b = bucket b, 64 nodes) ----------------

__global__ __launch_bounds__(256) void k_csr_enc_g0(const int* __restrict__ bcur, const int* __restrict__ colp,
                                                    int* __restrict__ cols, float* __restrict__ dinv,
                                                    int* __restrict__ rowst, int* __restrict__ rowen,
                                                    const float* __restrict__ x, const float* __restrict__ pos,
                                                    const float* __restrict__ encW, const float* __restrict__ encb,
                                                    const unsigned short* __restrict__ Wf,
                                                    const float* __restrict__ cb, const float* __restrict__ rb,
                                                    unsigned short* __restrict__ hWout,
                                                    float* __restrict__ X0, float* __restrict__ agg) {
  __shared__ int hist[64];
  __shared__ int excl[65];
  __shared__ float Ws[16 * 64];
  __shared__ float bs[64];
  int t = threadIdx.x;
  int b = blockIdx.x;

  for (int i = t; i < 1024; i += 256) Ws[i] = encW[i];
  if (t < 64) bs[t] = encb[t];

  int base = b * CAP;
  int cnt = bcur[b];
  if (t < 64) hist[t] = 0;
  __syncthreads();
  for (int e = t; e < cnt; e += 256) atomicAdd(&hist[colp[base + e] & 63], 1);
  __syncthreads();
  if (t == 0) {
    int run = 0;
#pragma unroll
    for (int i = 0; i < 64; i++) { excl[i] = run; run += hist[i]; }
    excl[64] = run;
  }
  __syncthreads();
  if (t < 64) {
    int n = b * 64 + t;
    rowst[n] = base + excl[t];
    rowen[n] = base + excl[t + 1];
    if (n < NN) dinv[n] = rsqrtf((float)(hist[t] + 1));  // +1 self-loop
    hist[t] = 0;  // reuse as cursor
  }
  __syncthreads();
  for (int e = t; e < cnt; e += 256) {
    int w = colp[base + e];
    int d = w & 63;
    int r = atomicAdd(&hist[d], 1);
    cols[base + excl[d] + r] = w >> 6;
  }

  // encoder for this bucket's 64 rows (no barrier needed vs cols scatter: disjoint data)
  int h = t & 63;
  int nset = t >> 6;
#pragma unroll
  for (int i = 0; i < 16; i++) {
    int n = b * 64 + nset * 16 + i;
    if (n < NN) {
      const float* xr = x + n * 14;
      float acc = bs[h];
#pragma unroll
      for (int f = 0; f < 14; f++) acc += xr[f] * Ws[f * 64 + h];
      acc += pos[n * 2 + 0] * Ws[14 * 64 + h];
      acc += pos[n * 2 + 1] * Ws[15 * 64 + h];
      X0[(size_t)n * 64 + h] = acc;
    }
  }
  __syncthreads();  // X0 + dinv visible block-wide (same CU)

  // gemm0 (mode 0): 4 waves x 16 rows x 64 cols
  int lane = t & 63;
  int wv = t >> 6;
  gemm_tile<4, 0>(lane, b * 64 + wv * 16, 0, X0, (const unsigned short*)0, Wf, cb, rb, dinv, hWout, agg);
}

// ---------------- gather inner step: 2 edges' h-pair per lane, zero-row padding ----------------

#define GSTEP(K)                                          \
  {                                                       \
    int e = j + 2 * (K) + p;                              \
    int s = __shfl(colv, e, 64);                          \
    s = e < cnt ? s : ZR;                                 \
    unsigned u = hW32[(unsigned)s * 32u + (unsigned)h2];  \
    a0 += __uint_as_float(u << 16);                       \
    a1 += __uint_as_float(u & 0xffff0000u);               \
  }

// ---------------- fused: gather layer l (-> gsum, block-local) + gemm layer l+1 ----------------
// 512 threads: gather = 8 waves x 8 nodes; gemm = 8 waves x (16 rows x 32 cols).
// hW double-buffered: gather reads hWin (prev launch), gemm writes hWout (next) -> no cross-block race.

__global__ __launch_bounds__(512) void k_gather_gemm(const int* __restrict__ rowst, const int* __restrict__ rowen,
                                                     const int* __restrict__ cols,
                                                     const unsigned short* __restrict__ hWin,
                                                     unsigned short* __restrict__ hWout,
                                                     unsigned short* __restrict__ gsum,
                                                     const unsigned short* __restrict__ Wf,
                                                     const float* __restrict__ cb, const float* __restrict__ rb,
                                                     const float* __restrict__ dinv,
                                                     const float* __restrict__ aggIn, float* __restrict__ aggOut) {
  int t = threadIdx.x;
  int lane = t & 63;
  int wv = t >> 6;
  int b = blockIdx.x;
  int h2 = lane & 31;
  int p = lane >> 5;
  const unsigned* __restrict__ hW32 = (const unsigned*)hWin;
  unsigned* __restrict__ gs32 = (unsigned*)gsum;

#pragma unroll 2
  for (int i = 0; i < 8; i++) {
    int n = __builtin_amdgcn_readfirstlane(b * 64 + wv * 8 + i);
    int st = rowst[n];
    int en = rowen[n];
    int deg = en - st;
    float a0 = 0.f, a1 = 0.f;
    for (int base2 = 0; base2 < deg; base2 += 64) {
      int cnt = deg - base2;
      if (cnt > 64) cnt = 64;
      int li = lane < cnt ? lane : cnt - 1;
      int colv = cols[st + base2 + li];
      for (int j = 0; j < cnt; j += 16) {
        GSTEP(0) GSTEP(1) GSTEP(2) GSTEP(3) GSTEP(4) GSTEP(5) GSTEP(6) GSTEP(7)
      }
    }
    a0 += __shfl_down(a0, 32, 64);
    a1 += __shfl_down(a1, 32, 64);
    if (lane < 32) gs32[(unsigned)n * 32u + (unsigned)h2] = (unsigned)f2bf(a0) | ((unsigned)f2bf(a1) << 16);
  }
  __syncthreads();  // gsum rows of this bucket visible block-wide (same CU)

  // gemm layer l+1 (mode 1): wave wv -> row-tile wv>>1, col-half wv&1
  int rt = wv >> 1, ch = wv & 1;
  gemm_tile<2, 1>(lane, b * 64 + rt * 16, ch * 2, aggIn, gsum, Wf, cb, rb, dinv, hWout, aggOut);
}

// ---------------- final gather + decode + atomic pool (high-parallelism shape) ----------------

__global__ __launch_bounds__(256) void k_gather_final(const int* __restrict__ rowst, const int* __restrict__ rowen,
                                                      const int* __restrict__ cols,
                                                      const unsigned short* __restrict__ hWin,
                                                      const float* __restrict__ aggIn, const float* __restrict__ dinv,
                                                      const float* __restrict__ decW, const float* __restrict__ decb,
                                                      const int* __restrict__ batch, float* __restrict__ out) {
  int t = threadIdx.x;
  int lane = t & 63;
  int h2 = lane & 31;
  int p = lane >> 5;
  int n = __builtin_amdgcn_readfirstlane(blockIdx.x * 4 + (t >> 6));
  const unsigned* __restrict__ hW32 = (const unsigned*)hWin;
  int st = rowst[n];
  int en = rowen[n];
  int deg = en - st;
  float a0 = 0.f, a1 = 0.f;
  for (int base2 = 0; base2 < deg; base2 += 64) {
    int cnt = deg - base2;
    if (cnt > 64) cnt = 64;
    int li = lane < cnt ? lane : cnt - 1;
    int colv = cols[st + base2 + li];
    for (int j = 0; j < cnt; j += 16) {
      GSTEP(0) GSTEP(1) GSTEP(2) GSTEP(3) GSTEP(4) GSTEP(5) GSTEP(6) GSTEP(7)
    }
  }
  a0 += __shfl_down(a0, 32, 64);
  a1 += __shfl_down(a1, 32, 64);
  float dv = dinv[n];
  float2 ag = *(const float2*)(aggIn + (size_t)n * 64 + h2 * 2);  // valid addr for all lanes
  float v = fmaxf(ag.x + dv * a0, 0.f) * decW[h2 * 2] + fmaxf(ag.y + dv * a1, 0.f) * decW[h2 * 2 + 1];
  v = (lane < 32) ? v : 0.f;  // upper half holds stale partials -> zero them
#pragma unroll
  for (int off = 32; off > 0; off >>= 1) v += __shfl_down(v, off, 64);
  if (lane == 0) atomicAdd(&out[batch[n]], v + decb[0]);
}

// ---------------- launch: 8 dispatches total ----------------

extern "C" void kernel_launch(void* const* d_in, const int* in_sizes, int n_in,
                              void* d_out, int out_size, void* d_ws, size_t ws_size,
                              hipStream_t stream) {
  (void)in_sizes; (void)n_in; (void)out_size; (void)ws_size;
  const float* x     = (const float*)d_in[0];
  const float* pos   = (const float*)d_in[1];
  const int*   ei    = (const int*)d_in[2];
  const int*   batch = (const int*)d_in[3];
  const float* encW  = (const float*)d_in[4];
  const float* encb  = (const float*)d_in[5];
  const float* convW = (const float*)d_in[6];
  const float* convb = (const float*)d_in[7];
  const float* resW  = (const float*)d_in[8];
  const float* resb  = (const float*)d_in[9];
  const float* decW  = (const float*)d_in[10];
  const float* decb  = (const float*)d_in[11];
  float* out = (float*)d_out;

  const int* src = ei;       // edge_index[0]
  const int* dst = ei + NE;  // edge_index[1]

  // workspace layout (4-byte elems)
  float*          ws    = (float*)d_ws;
  float*          dinv  = ws;                                  // [NPAD]
  int*            rowst = (int*)(ws + NPAD);                   // [NPAD]
  int*            rowen = (int*)(ws + 2 * NPAD);               // [NPAD]
  int*            bcur  = (int*)(ws + 3 * NPAD);               // [1024]
  int*            colp  = bcur + 1024;                         // [NBKT*CAP]
  int*            cols  = colp + NBKT * CAP;                   // [NBKT*CAP]
  unsigned short* hWA   = (unsigned short*)(cols + NBKT * CAP);  // [NPAD*64] bf16
  unsigned short* hWB   = hWA + (size_t)NPAD * 64;               // [NPAD*64] bf16
  unsigned short* gsum  = hWB + (size_t)NPAD * 64;               // [NPAD*64] bf16
  float*          bufA  = (float*)(gsum + (size_t)NPAD * 64);    // [NN*NH]
  float*          bufB  = bufA + NN * NH;                        // [NN*NH]
  unsigned short* Wf    = (unsigned short*)(bufB + NN * NH);     // [32*512] bf16 frag W

  k_prep<<<9, 256, 0, stream>>>(convW, resW, Wf, bcur, out, hWA, hWB);
  k_bin<<<(NE + 8191) / 8192, 256, 0, stream>>>(src, dst, bcur, colp);
  k_csr_enc_g0<<<NBKT, 256, 0, stream>>>(bcur, colp, cols, dinv, rowst, rowen,
                                         x, pos, encW, encb, Wf, convb, resb,
                                         hWA, bufA, bufB);
  // layers 1..4: gather prev hW + gemm next. hW ping-pongs A->B->A->B->A; agg B->A->B->A->B.
  k_gather_gemm<<<NBKT, 512, 0, stream>>>(rowst, rowen, cols, hWA, hWB, gsum, Wf, convb, resb, dinv, bufB, bufA);
  k_gather_gemm<<<NBKT, 512, 0, stream>>>(rowst, rowen, cols, hWB, hWA, gsum, Wf, convb, resb, dinv, bufA, bufB);
  k_gather_gemm<<<NBKT, 512, 0, stream>>>(rowst, rowen, cols, hWA, hWB, gsum, Wf, convb, resb, dinv, bufB, bufA);
  k_gather_gemm<<<NBKT, 512, 0, stream>>>(rowst, rowen, cols, hWB, hWA, gsum, Wf, convb, resb, dinv, bufA, bufB);
  // final: gather hW_4 (=hWA) + decode with agg_4 (=bufB) + atomic pooling
  k_gather_final<<<NN / 4, 256, 0, stream>>>(rowst, rowen, cols, hWA, bufB, dinv, decW, decb, batch, out);
}